// Round 1
// baseline (2341.544 us; speedup 1.0000x reference)
//
#include <hip/hip_runtime.h>

#define RR 48
#define GG 300
#define HW2 (GG * GG)
#define NPLANE (RR * HW2)
#define NVEC (RR * GG)
#define CC 27

struct Axis { int i0, i1; float f; };

__device__ __forceinline__ Axis axis_interp(float x) {
  // mirror reference arithmetic exactly: g = 2x-1; ih = (g+1)*0.5*(G-1)
  float g = x * 2.0f - 1.0f;
  float ih = (g + 1.0f) * 0.5f * (float)(GG - 1);
  int i0 = (int)floorf(ih);
  i0 = i0 < 0 ? 0 : (i0 > GG - 1 ? GG - 1 : i0);
  int i1 = i0 + 1 > GG - 1 ? GG - 1 : i0 + 1;
  Axis a;
  a.i0 = i0; a.i1 = i1;
  a.f = ih - (float)i0;
  return a;
}

// One segment: bilinear(P at (ai,aj)) * linear(V at ak), then acc += feat_r * F[r][c]
template <int TR>
__device__ __forceinline__ void seg(const float* __restrict__ P, Axis ai, Axis aj,
                                    const float* __restrict__ V, Axis ak,
                                    const float* __restrict__ F, float acc[CC]) {
  float fi = ai.f, fj = aj.f, fk = ak.f;
  float w00 = (1.f - fi) * (1.f - fj);
  float w01 = (1.f - fi) * fj;
  float w10 = fi * (1.f - fj);
  float w11 = fi * fj;
  float omk = 1.f - fk;

  if (TR) {
    // transposed layout: P[(i*GG + j)*RR + r], V[k*RR + r]
    int b00 = (ai.i0 * GG + aj.i0) * RR;
    int b01 = (ai.i0 * GG + aj.i1) * RR;
    int b10 = (ai.i1 * GG + aj.i0) * RR;
    int b11 = (ai.i1 * GG + aj.i1) * RR;
    int v0 = ak.i0 * RR;
    int v1 = ak.i1 * RR;
#pragma unroll 1
    for (int r = 0; r < RR; r += 4) {
      float4 p00 = *(const float4*)(P + b00 + r);
      float4 p01 = *(const float4*)(P + b01 + r);
      float4 p10 = *(const float4*)(P + b10 + r);
      float4 p11 = *(const float4*)(P + b11 + r);
      float4 a0 = *(const float4*)(V + v0 + r);
      float4 a1 = *(const float4*)(V + v1 + r);
      float ft[4];
      ft[0] = (w00 * p00.x + w01 * p01.x + w10 * p10.x + w11 * p11.x) * (omk * a0.x + fk * a1.x);
      ft[1] = (w00 * p00.y + w01 * p01.y + w10 * p10.y + w11 * p11.y) * (omk * a0.y + fk * a1.y);
      ft[2] = (w00 * p00.z + w01 * p01.z + w10 * p10.z + w11 * p11.z) * (omk * a0.z + fk * a1.z);
      ft[3] = (w00 * p00.w + w01 * p01.w + w10 * p10.w + w11 * p11.w) * (omk * a0.w + fk * a1.w);
      const float* Fr = F + r * CC;
#pragma unroll
      for (int q = 0; q < 4; ++q) {
        const float* Fq = Fr + q * CC;  // uniform address -> should scalarize to s_load
        float fv = ft[q];
#pragma unroll
        for (int c = 0; c < CC; ++c) acc[c] = fmaf(fv, Fq[c], acc[c]);
      }
    }
  } else {
    // fallback: original layout P[r*HW2 + i*GG + j], V[r*GG + k]
#pragma unroll 1
    for (int r = 0; r < RR; ++r) {
      const float* pr = P + r * HW2;
      float p00 = pr[ai.i0 * GG + aj.i0];
      float p01 = pr[ai.i0 * GG + aj.i1];
      float p10 = pr[ai.i1 * GG + aj.i0];
      float p11 = pr[ai.i1 * GG + aj.i1];
      float a0 = V[r * GG + ak.i0];
      float a1 = V[r * GG + ak.i1];
      float ft = (w00 * p00 + w01 * p01 + w10 * p10 + w11 * p11) * (omk * a0 + fk * a1);
      const float* Fr = F + r * CC;
#pragma unroll
      for (int c = 0; c < CC; ++c) acc[c] = fmaf(ft, Fr[c], acc[c]);
    }
  }
}

template <int TR>
__global__ void __launch_bounds__(256) tensorf_main(
    const float* __restrict__ xyz,
    const float* __restrict__ Pxy, const float* __restrict__ Pxz, const float* __restrict__ Pyz,
    const float* __restrict__ Vx, const float* __restrict__ Vy, const float* __restrict__ Vz,
    const float* __restrict__ F,
    float* __restrict__ out, int n) {
  int idx = blockIdx.x * blockDim.x + threadIdx.x;
  if (idx >= n) return;
  float x = xyz[idx * 3 + 0];
  float y = xyz[idx * 3 + 1];
  float z = xyz[idx * 3 + 2];
  Axis ax = axis_interp(x), ay = axis_interp(y), az = axis_interp(z);

  float acc[CC];
#pragma unroll
  for (int c = 0; c < CC; ++c) acc[c] = 0.f;

  // feat = [xy*z | xz*y | yz*x] @ F
  seg<TR>(Pxy, ax, ay, Vz, az, F + 0 * RR * CC, acc);
  seg<TR>(Pxz, ax, az, Vy, ay, F + 1 * RR * CC, acc);
  seg<TR>(Pyz, ay, az, Vx, ax, F + 2 * RR * CC, acc);

  float* o = out + (size_t)idx * CC;
#pragma unroll
  for (int c = 0; c < CC; ++c) o[c] = acc[c];
}

// [R, HW2] -> [HW2, R]
__global__ void __launch_bounds__(256) transpose_plane(const float* __restrict__ in,
                                                       float* __restrict__ out) {
  __shared__ float tile[256 * 49];  // +1 pad on R-dim stride to kill bank conflicts
  int base = blockIdx.x * 256;
  int t = threadIdx.x;
  int pos = base + t;
#pragma unroll 1
  for (int r = 0; r < RR; ++r) {
    float v = (pos < HW2) ? in[r * HW2 + pos] : 0.f;
    tile[t * 49 + r] = v;
  }
  __syncthreads();
#pragma unroll 1
  for (int k = t; k < 256 * RR; k += 256) {
    int p = k / RR;
    int r = k - p * RR;
    int hw = base + p;
    if (hw < HW2) out[hw * RR + r] = tile[p * 49 + r];
  }
}

// [R, GG] -> [GG, R]
__global__ void __launch_bounds__(256) transpose_vec(const float* __restrict__ in,
                                                     float* __restrict__ out) {
  int tid = blockIdx.x * blockDim.x + threadIdx.x;
  if (tid < GG * RR) {
    int i = tid / RR;
    int r = tid - i * RR;
    out[tid] = in[r * GG + i];
  }
}

extern "C" void kernel_launch(void* const* d_in, const int* in_sizes, int n_in,
                              void* d_out, int out_size, void* d_ws, size_t ws_size,
                              hipStream_t stream) {
  const float* xyz = (const float*)d_in[0];
  const float* pxy = (const float*)d_in[1];
  const float* pxz = (const float*)d_in[2];
  const float* pyz = (const float*)d_in[3];
  const float* vx = (const float*)d_in[4];
  const float* vy = (const float*)d_in[5];
  const float* vz = (const float*)d_in[6];
  const float* F = (const float*)d_in[7];
  float* out = (float*)d_out;
  int n = in_sizes[0] / 3;
  int nblk = (n + 255) / 256;

  size_t need = (size_t)(3 * NPLANE + 3 * NVEC) * sizeof(float);
  if (ws_size >= need) {
    float* w = (float*)d_ws;
    float* Txy = w;
    float* Txz = Txy + NPLANE;
    float* Tyz = Txz + NPLANE;
    float* Tx = Tyz + NPLANE;
    float* Ty = Tx + NVEC;
    float* Tz = Ty + NVEC;
    int tb = (HW2 + 255) / 256;
    transpose_plane<<<tb, 256, 0, stream>>>(pxy, Txy);
    transpose_plane<<<tb, 256, 0, stream>>>(pxz, Txz);
    transpose_plane<<<tb, 256, 0, stream>>>(pyz, Tyz);
    int vb = (GG * RR + 255) / 256;
    transpose_vec<<<vb, 256, 0, stream>>>(vx, Tx);
    transpose_vec<<<vb, 256, 0, stream>>>(vy, Ty);
    transpose_vec<<<vb, 256, 0, stream>>>(vz, Tz);
    tensorf_main<1><<<nblk, 256, 0, stream>>>(xyz, Txy, Txz, Tyz, Tx, Ty, Tz, F, out, n);
  } else {
    tensorf_main<0><<<nblk, 256, 0, stream>>>(xyz, pxy, pxz, pyz, vx, vy, vz, F, out, n);
  }
}

// Round 2
// 880.014 us; speedup vs baseline: 2.6608x; 2.6608x over previous
//
#include <hip/hip_runtime.h>

#define RR 48
#define GG 300
#define HW2 (GG * GG)
#define NPLANE (RR * HW2)
#define NVEC (RR * GG)
#define CC 27
#define NBUCK 32768  // 32^3 Morton buckets

struct Axis { int i0, i1; float f; };

__device__ __forceinline__ Axis axis_interp(float x) {
  float g = x * 2.0f - 1.0f;
  float ih = (g + 1.0f) * 0.5f * (float)(GG - 1);
  int i0 = (int)floorf(ih);
  i0 = i0 < 0 ? 0 : (i0 > GG - 1 ? GG - 1 : i0);
  int i1 = i0 + 1 > GG - 1 ? GG - 1 : i0 + 1;
  Axis a; a.i0 = i0; a.i1 = i1; a.f = ih - (float)i0;
  return a;
}

// bilinear(P at (ai,aj)) * linear(V at ak) -> acc += feat_r * F[r][c]
// transposed layout: P[(i*GG + j)*RR + r], V[k*RR + r]
__device__ __forceinline__ void seg_t(const float* __restrict__ P, Axis ai, Axis aj,
                                      const float* __restrict__ V, Axis ak,
                                      const float* __restrict__ F, float acc[CC]) {
  float fi = ai.f, fj = aj.f, fk = ak.f;
  float w00 = (1.f - fi) * (1.f - fj);
  float w01 = (1.f - fi) * fj;
  float w10 = fi * (1.f - fj);
  float w11 = fi * fj;
  float omk = 1.f - fk;
  int b00 = (ai.i0 * GG + aj.i0) * RR;
  int b01 = (ai.i0 * GG + aj.i1) * RR;
  int b10 = (ai.i1 * GG + aj.i0) * RR;
  int b11 = (ai.i1 * GG + aj.i1) * RR;
  int v0 = ak.i0 * RR;
  int v1 = ak.i1 * RR;
#pragma unroll 1
  for (int r = 0; r < RR; r += 4) {
    float4 p00 = *(const float4*)(P + b00 + r);
    float4 p01 = *(const float4*)(P + b01 + r);
    float4 p10 = *(const float4*)(P + b10 + r);
    float4 p11 = *(const float4*)(P + b11 + r);
    float4 a0 = *(const float4*)(V + v0 + r);
    float4 a1 = *(const float4*)(V + v1 + r);
    float ft[4];
    ft[0] = (w00 * p00.x + w01 * p01.x + w10 * p10.x + w11 * p11.x) * (omk * a0.x + fk * a1.x);
    ft[1] = (w00 * p00.y + w01 * p01.y + w10 * p10.y + w11 * p11.y) * (omk * a0.y + fk * a1.y);
    ft[2] = (w00 * p00.z + w01 * p01.z + w10 * p10.z + w11 * p11.z) * (omk * a0.z + fk * a1.z);
    ft[3] = (w00 * p00.w + w01 * p01.w + w10 * p10.w + w11 * p11.w) * (omk * a0.w + fk * a1.w);
    const float* Fr = F + r * CC;
#pragma unroll
    for (int q = 0; q < 4; ++q) {
      const float* Fq = Fr + q * CC;  // wave-uniform address
      float fv = ft[q];
#pragma unroll
      for (int c = 0; c < CC; ++c) acc[c] = fmaf(fv, Fq[c], acc[c]);
    }
  }
}

// original layout fallback
__device__ __forceinline__ void seg_n(const float* __restrict__ P, Axis ai, Axis aj,
                                      const float* __restrict__ V, Axis ak,
                                      const float* __restrict__ F, float acc[CC]) {
  float fi = ai.f, fj = aj.f, fk = ak.f;
  float w00 = (1.f - fi) * (1.f - fj);
  float w01 = (1.f - fi) * fj;
  float w10 = fi * (1.f - fj);
  float w11 = fi * fj;
  float omk = 1.f - fk;
#pragma unroll 1
  for (int r = 0; r < RR; ++r) {
    const float* pr = P + r * HW2;
    float p00 = pr[ai.i0 * GG + aj.i0];
    float p01 = pr[ai.i0 * GG + aj.i1];
    float p10 = pr[ai.i1 * GG + aj.i0];
    float p11 = pr[ai.i1 * GG + aj.i1];
    float a0 = V[r * GG + ak.i0];
    float a1 = V[r * GG + ak.i1];
    float ft = (w00 * p00 + w01 * p01 + w10 * p10 + w11 * p11) * (omk * a0 + fk * a1);
    const float* Fr = F + r * CC;
#pragma unroll
    for (int c = 0; c < CC; ++c) acc[c] = fmaf(ft, Fr[c], acc[c]);
  }
}

__device__ __forceinline__ unsigned part3(unsigned v) {  // 5 bits -> every 3rd bit
  unsigned r = 0;
  r |= (v & 1u);
  r |= (v & 2u) << 2;
  r |= (v & 4u) << 4;
  r |= (v & 8u) << 6;
  r |= (v & 16u) << 8;
  return r;
}

__device__ __forceinline__ int morton_key(float x, float y, float z) {
  int qx = (int)(x * 32.0f); qx = qx < 0 ? 0 : (qx > 31 ? 31 : qx);
  int qy = (int)(y * 32.0f); qy = qy < 0 ? 0 : (qy > 31 ? 31 : qy);
  int qz = (int)(z * 32.0f); qz = qz < 0 ? 0 : (qz > 31 ? 31 : qz);
  return (int)(part3((unsigned)qx) | (part3((unsigned)qy) << 1) | (part3((unsigned)qz) << 2));
}

__global__ void __launch_bounds__(256) hist_kernel(const float* __restrict__ xyz, int n,
                                                   int* __restrict__ offs) {
  int i = blockIdx.x * blockDim.x + threadIdx.x;
  if (i >= n) return;
  float x = xyz[i * 3 + 0], y = xyz[i * 3 + 1], z = xyz[i * 3 + 2];
  atomicAdd(&offs[morton_key(x, y, z)], 1);
}

__global__ void __launch_bounds__(1024) scan_kernel(int* __restrict__ offs) {
  __shared__ int part[1024];
  int t = threadIdx.x;
  int base = t * (NBUCK / 1024);
  int loc[NBUCK / 1024];
  int s = 0;
#pragma unroll
  for (int i = 0; i < NBUCK / 1024; ++i) { loc[i] = offs[base + i]; s += loc[i]; }
  part[t] = s;
  __syncthreads();
  for (int off = 1; off < 1024; off <<= 1) {
    int u = (t >= off) ? part[t - off] : 0;
    __syncthreads();
    part[t] += u;
    __syncthreads();
  }
  int excl = (t == 0) ? 0 : part[t - 1];
#pragma unroll
  for (int i = 0; i < NBUCK / 1024; ++i) {
    int c = loc[i];
    offs[base + i] = excl;
    excl += c;
  }
}

__global__ void __launch_bounds__(256) scatter_kernel(const float* __restrict__ xyz, int n,
                                                      int* __restrict__ offs,
                                                      float4* __restrict__ pts) {
  int i = blockIdx.x * blockDim.x + threadIdx.x;
  if (i >= n) return;
  float x = xyz[i * 3 + 0], y = xyz[i * 3 + 1], z = xyz[i * 3 + 2];
  int key = morton_key(x, y, z);
  int pos = atomicAdd(&offs[key], 1);
  float4 p;
  p.x = x; p.y = y; p.z = z;
  p.w = __int_as_float(i);
  pts[pos] = p;
}

// sorted main: block swizzle so each XCD streams one contiguous Morton octant
__global__ void __launch_bounds__(256) tensorf_sorted(
    const float4* __restrict__ pts,
    const float* __restrict__ Pxy, const float* __restrict__ Pxz, const float* __restrict__ Pyz,
    const float* __restrict__ Vx, const float* __restrict__ Vy, const float* __restrict__ Vz,
    const float* __restrict__ F,
    float* __restrict__ out, int n, int chunkLen) {
  int b = blockIdx.x;
  int newb = (b & 7) * chunkLen + (b >> 3);
  int t = newb * 256 + threadIdx.x;
  if (t >= n) return;
  float4 p = pts[t];
  Axis ax = axis_interp(p.x), ay = axis_interp(p.y), az = axis_interp(p.z);
  int oi = __float_as_int(p.w);

  float acc[CC];
#pragma unroll
  for (int c = 0; c < CC; ++c) acc[c] = 0.f;
  seg_t(Pxy, ax, ay, Vz, az, F + 0 * RR * CC, acc);
  seg_t(Pxz, ax, az, Vy, ay, F + 1 * RR * CC, acc);
  seg_t(Pyz, ay, az, Vx, ax, F + 2 * RR * CC, acc);

  float* o = out + (size_t)oi * CC;
#pragma unroll
  for (int c = 0; c < CC; ++c) o[c] = acc[c];
}

template <int TR>
__global__ void __launch_bounds__(256) tensorf_main(
    const float* __restrict__ xyz,
    const float* __restrict__ Pxy, const float* __restrict__ Pxz, const float* __restrict__ Pyz,
    const float* __restrict__ Vx, const float* __restrict__ Vy, const float* __restrict__ Vz,
    const float* __restrict__ F,
    float* __restrict__ out, int n) {
  int idx = blockIdx.x * blockDim.x + threadIdx.x;
  if (idx >= n) return;
  float x = xyz[idx * 3 + 0], y = xyz[idx * 3 + 1], z = xyz[idx * 3 + 2];
  Axis ax = axis_interp(x), ay = axis_interp(y), az = axis_interp(z);
  float acc[CC];
#pragma unroll
  for (int c = 0; c < CC; ++c) acc[c] = 0.f;
  if (TR) {
    seg_t(Pxy, ax, ay, Vz, az, F + 0 * RR * CC, acc);
    seg_t(Pxz, ax, az, Vy, ay, F + 1 * RR * CC, acc);
    seg_t(Pyz, ay, az, Vx, ax, F + 2 * RR * CC, acc);
  } else {
    seg_n(Pxy, ax, ay, Vz, az, F + 0 * RR * CC, acc);
    seg_n(Pxz, ax, az, Vy, ay, F + 1 * RR * CC, acc);
    seg_n(Pyz, ay, az, Vx, ax, F + 2 * RR * CC, acc);
  }
  float* o = out + (size_t)idx * CC;
#pragma unroll
  for (int c = 0; c < CC; ++c) o[c] = acc[c];
}

// [R, HW2] -> [HW2, R]
__global__ void __launch_bounds__(256) transpose_plane(const float* __restrict__ in,
                                                       float* __restrict__ out) {
  __shared__ float tile[256 * 49];
  int base = blockIdx.x * 256;
  int t = threadIdx.x;
  int pos = base + t;
#pragma unroll 1
  for (int r = 0; r < RR; ++r) {
    float v = (pos < HW2) ? in[r * HW2 + pos] : 0.f;
    tile[t * 49 + r] = v;
  }
  __syncthreads();
#pragma unroll 1
  for (int k = t; k < 256 * RR; k += 256) {
    int p = k / RR;
    int r = k - p * RR;
    int hw = base + p;
    if (hw < HW2) out[hw * RR + r] = tile[p * 49 + r];
  }
}

// [R, GG] -> [GG, R]
__global__ void __launch_bounds__(256) transpose_vec(const float* __restrict__ in,
                                                     float* __restrict__ out) {
  int tid = blockIdx.x * blockDim.x + threadIdx.x;
  if (tid < GG * RR) {
    int i = tid / RR;
    int r = tid - i * RR;
    out[tid] = in[r * GG + i];
  }
}

extern "C" void kernel_launch(void* const* d_in, const int* in_sizes, int n_in,
                              void* d_out, int out_size, void* d_ws, size_t ws_size,
                              hipStream_t stream) {
  const float* xyz = (const float*)d_in[0];
  const float* pxy = (const float*)d_in[1];
  const float* pxz = (const float*)d_in[2];
  const float* pyz = (const float*)d_in[3];
  const float* vx = (const float*)d_in[4];
  const float* vy = (const float*)d_in[5];
  const float* vz = (const float*)d_in[6];
  const float* F = (const float*)d_in[7];
  float* out = (float*)d_out;
  int n = in_sizes[0] / 3;
  int nblk = (n + 255) / 256;

  size_t transBytes = (size_t)(3 * NPLANE + 3 * NVEC) * sizeof(float);
  size_t sortBytes = transBytes + (size_t)NBUCK * sizeof(int) + (size_t)n * sizeof(float4);

  if (ws_size >= sortBytes) {
    // tier S: transposed planes + Morton-sorted points
    float* w = (float*)d_ws;
    float* Txy = w;
    float* Txz = Txy + NPLANE;
    float* Tyz = Txz + NPLANE;
    float* Tx = Tyz + NPLANE;
    float* Ty = Tx + NVEC;
    float* Tz = Ty + NVEC;
    int* offs = (int*)(Tz + NVEC);
    float4* pts = (float4*)(offs + NBUCK);

    int tb = (HW2 + 255) / 256;
    transpose_plane<<<tb, 256, 0, stream>>>(pxy, Txy);
    transpose_plane<<<tb, 256, 0, stream>>>(pxz, Txz);
    transpose_plane<<<tb, 256, 0, stream>>>(pyz, Tyz);
    int vb = (GG * RR + 255) / 256;
    transpose_vec<<<vb, 256, 0, stream>>>(vx, Tx);
    transpose_vec<<<vb, 256, 0, stream>>>(vy, Ty);
    transpose_vec<<<vb, 256, 0, stream>>>(vz, Tz);

    hipMemsetAsync(offs, 0, (size_t)NBUCK * sizeof(int), stream);
    hist_kernel<<<nblk, 256, 0, stream>>>(xyz, n, offs);
    scan_kernel<<<1, 1024, 0, stream>>>(offs);
    scatter_kernel<<<nblk, 256, 0, stream>>>(xyz, n, offs, pts);

    int chunkLen = (nblk + 7) / 8;
    tensorf_sorted<<<chunkLen * 8, 256, 0, stream>>>(pts, Txy, Txz, Tyz, Tx, Ty, Tz, F, out, n,
                                                     chunkLen);
  } else if (ws_size >= transBytes) {
    // tier T: transposed planes only (R1 behavior)
    float* w = (float*)d_ws;
    float* Txy = w;
    float* Txz = Txy + NPLANE;
    float* Tyz = Txz + NPLANE;
    float* Tx = Tyz + NPLANE;
    float* Ty = Tx + NVEC;
    float* Tz = Ty + NVEC;
    int tb = (HW2 + 255) / 256;
    transpose_plane<<<tb, 256, 0, stream>>>(pxy, Txy);
    transpose_plane<<<tb, 256, 0, stream>>>(pxz, Txz);
    transpose_plane<<<tb, 256, 0, stream>>>(pyz, Tyz);
    int vb = (GG * RR + 255) / 256;
    transpose_vec<<<vb, 256, 0, stream>>>(vx, Tx);
    transpose_vec<<<vb, 256, 0, stream>>>(vy, Ty);
    transpose_vec<<<vb, 256, 0, stream>>>(vz, Tz);
    tensorf_main<1><<<nblk, 256, 0, stream>>>(xyz, Txy, Txz, Tyz, Tx, Ty, Tz, F, out, n);
  } else {
    tensorf_main<0><<<nblk, 256, 0, stream>>>(xyz, pxy, pxz, pyz, vx, vy, vz, F, out, n);
  }
}

// Round 3
// 730.667 us; speedup vs baseline: 3.2047x; 1.2044x over previous
//
#include <hip/hip_runtime.h>

#define RR 48
#define GG 300
#define HW2 (GG * GG)
#define NPLANE (RR * HW2)
#define NVEC (RR * GG)
#define CC 27
#define NBUCK 32768  // 32^3 Morton buckets
#define TP 128       // points per block tile
#define TPP 129      // padded LDS column count

struct Axis { int i0, i1; float f; };

__device__ __forceinline__ Axis axis_interp(float x) {
  float g = x * 2.0f - 1.0f;
  float ih = (g + 1.0f) * 0.5f * (float)(GG - 1);
  int i0 = (int)floorf(ih);
  i0 = i0 < 0 ? 0 : (i0 > GG - 1 ? GG - 1 : i0);
  int i1 = i0 + 1 > GG - 1 ? GG - 1 : i0 + 1;
  Axis a; a.i0 = i0; a.i1 = i1; a.f = ih - (float)i0;
  return a;
}

// ---------------- sort machinery ----------------
__device__ __forceinline__ unsigned part3(unsigned v) {
  unsigned r = 0;
  r |= (v & 1u);
  r |= (v & 2u) << 2;
  r |= (v & 4u) << 4;
  r |= (v & 8u) << 6;
  r |= (v & 16u) << 8;
  return r;
}

__device__ __forceinline__ int morton_key(float x, float y, float z) {
  int qx = (int)(x * 32.0f); qx = qx < 0 ? 0 : (qx > 31 ? 31 : qx);
  int qy = (int)(y * 32.0f); qy = qy < 0 ? 0 : (qy > 31 ? 31 : qy);
  int qz = (int)(z * 32.0f); qz = qz < 0 ? 0 : (qz > 31 ? 31 : qz);
  return (int)(part3((unsigned)qx) | (part3((unsigned)qy) << 1) | (part3((unsigned)qz) << 2));
}

__global__ void __launch_bounds__(256) hist_kernel(const float* __restrict__ xyz, int n,
                                                   int* __restrict__ offs) {
  int i = blockIdx.x * blockDim.x + threadIdx.x;
  if (i >= n) return;
  atomicAdd(&offs[morton_key(xyz[i * 3], xyz[i * 3 + 1], xyz[i * 3 + 2])], 1);
}

__global__ void __launch_bounds__(1024) scan_kernel(int* __restrict__ offs) {
  __shared__ int part[1024];
  int t = threadIdx.x;
  int base = t * (NBUCK / 1024);
  int loc[NBUCK / 1024];
  int s = 0;
#pragma unroll
  for (int i = 0; i < NBUCK / 1024; ++i) { loc[i] = offs[base + i]; s += loc[i]; }
  part[t] = s;
  __syncthreads();
  for (int off = 1; off < 1024; off <<= 1) {
    int u = (t >= off) ? part[t - off] : 0;
    __syncthreads();
    part[t] += u;
    __syncthreads();
  }
  int excl = (t == 0) ? 0 : part[t - 1];
#pragma unroll
  for (int i = 0; i < NBUCK / 1024; ++i) {
    int c = loc[i];
    offs[base + i] = excl;
    excl += c;
  }
}

__global__ void __launch_bounds__(256) scatter_kernel(const float* __restrict__ xyz, int n,
                                                      int* __restrict__ offs,
                                                      int* __restrict__ sidx) {
  int i = blockIdx.x * blockDim.x + threadIdx.x;
  if (i >= n) return;
  int key = morton_key(xyz[i * 3], xyz[i * 3 + 1], xyz[i * 3 + 2]);
  int pos = atomicAdd(&offs[key], 1);
  sidx[pos] = i;
}

// ---------------- layout transforms ----------------
// [R, HW2] -> [HW2, R], 3 planes via gridDim.y
__global__ void __launch_bounds__(256) transpose_planes(const float* __restrict__ p0,
                                                        const float* __restrict__ p1,
                                                        const float* __restrict__ p2,
                                                        float* __restrict__ t0,
                                                        float* __restrict__ t1,
                                                        float* __restrict__ t2) {
  __shared__ float tile[256 * 49];
  const float* in = (blockIdx.y == 0) ? p0 : (blockIdx.y == 1) ? p1 : p2;
  float* out = (blockIdx.y == 0) ? t0 : (blockIdx.y == 1) ? t1 : t2;
  int base = blockIdx.x * 256;
  int t = threadIdx.x;
  int pos = base + t;
#pragma unroll 1
  for (int r = 0; r < RR; ++r) {
    float v = (pos < HW2) ? in[r * HW2 + pos] : 0.f;
    tile[t * 49 + r] = v;
  }
  __syncthreads();
#pragma unroll 1
  for (int k = t; k < 256 * RR; k += 256) {
    int p = k / RR;
    int r = k - p * RR;
    int hw = base + p;
    if (hw < HW2) out[hw * RR + r] = tile[p * 49 + r];
  }
}

// [R, GG] -> [GG, R], all 3 vecs in one grid
__global__ void __launch_bounds__(256) transpose_vecs(const float* __restrict__ v0,
                                                      const float* __restrict__ v1,
                                                      const float* __restrict__ v2,
                                                      float* __restrict__ t0,
                                                      float* __restrict__ t1,
                                                      float* __restrict__ t2) {
  int e = blockIdx.x * blockDim.x + threadIdx.x;
  if (e >= 3 * NVEC) return;
  int v = e / NVEC;
  int rem = e - v * NVEC;
  int i = rem / RR;
  int r = rem - i * RR;
  const float* in = (v == 0) ? v0 : (v == 1) ? v1 : v2;
  float* out = (v == 0) ? t0 : (v == 1) ? t1 : t2;
  out[i * RR + r] = in[r * GG + i];
}

// ---------------- fused main ----------------
// One corner-run gather + interpolation for one seg; lane l<12 covers channels 4l..4l+3.
__device__ __forceinline__ void gather_seg(const float* __restrict__ P, Axis ai, Axis aj,
                                           const float* __restrict__ V, Axis ak,
                                           int r4, float* __restrict__ dst) {
  float fi = ai.f, fj = aj.f, fk = ak.f;
  float w00 = (1.f - fi) * (1.f - fj);
  float w01 = (1.f - fi) * fj;
  float w10 = fi * (1.f - fj);
  float w11 = fi * fj;
  float omk = 1.f - fk;
  float4 q00 = *(const float4*)(P + (ai.i0 * GG + aj.i0) * RR + r4);
  float4 q01 = *(const float4*)(P + (ai.i0 * GG + aj.i1) * RR + r4);
  float4 q10 = *(const float4*)(P + (ai.i1 * GG + aj.i0) * RR + r4);
  float4 q11 = *(const float4*)(P + (ai.i1 * GG + aj.i1) * RR + r4);
  float4 b0 = *(const float4*)(V + ak.i0 * RR + r4);
  float4 b1 = *(const float4*)(V + ak.i1 * RR + r4);
  float t0 = (w00 * q00.x + w01 * q01.x + w10 * q10.x + w11 * q11.x) * (omk * b0.x + fk * b1.x);
  float t1 = (w00 * q00.y + w01 * q01.y + w10 * q10.y + w11 * q11.y) * (omk * b0.y + fk * b1.y);
  float t2 = (w00 * q00.z + w01 * q01.z + w10 * q10.z + w11 * q11.z) * (omk * b0.z + fk * b1.z);
  float t3 = (w00 * q00.w + w01 * q01.w + w10 * q10.w + w11 * q11.w) * (omk * b0.w + fk * b1.w);
  dst[(r4 + 0) * TPP] = t0;
  dst[(r4 + 1) * TPP] = t1;
  dst[(r4 + 2) * TPP] = t2;
  dst[(r4 + 3) * TPP] = t3;
}

__global__ void __launch_bounds__(256) tensorf_fused(
    const int* __restrict__ sidx, const float* __restrict__ xyz,
    const float* __restrict__ Txy, const float* __restrict__ Txz, const float* __restrict__ Tyz,
    const float* __restrict__ Tx, const float* __restrict__ Ty, const float* __restrict__ Tz,
    const float* __restrict__ F, float* __restrict__ out, int n, int chunkLen) {
  __shared__ float featT[144 * TPP];  // 74.3 KB -> 2 blocks/CU
  int b = blockIdx.x;
  int nb = (b & 7) * chunkLen + (b >> 3);  // XCD-aware: each XCD streams one Morton chunk
  int base = nb * TP;
  int tid = threadIdx.x;
  int g = tid >> 4;   // group 0..15, one point per group per iter
  int l = tid & 15;   // lane within group; lanes 0..11 do the loads

  // ---- phase 1: coalesced gather + interpolate -> featT[144][TP] ----
#pragma unroll 1
  for (int it = 0; it < TP / 16; ++it) {
    int pl = g + (it << 4);
    int sp = base + pl;
    if (sp < n) {
      int oi = sidx[sp];                       // broadcast within group
      float x = xyz[oi * 3 + 0];
      float y = xyz[oi * 3 + 1];
      float z = xyz[oi * 3 + 2];
      Axis ax = axis_interp(x), ay = axis_interp(y), az = axis_interp(z);
      if (l < 12) {
        int r4 = l << 2;
        float* dst = &featT[pl];
        gather_seg(Txy, ax, ay, Tz, az, r4, dst + 0 * RR * TPP);
        gather_seg(Txz, ax, az, Ty, ay, r4, dst + 1 * RR * TPP);
        gather_seg(Tyz, ay, az, Tx, ax, r4, dst + 2 * RR * TPP);
      }
    }
  }
  __syncthreads();

  // ---- phase 2: feat[144] @ F[144][27], 2 threads per point ----
  int p = tid & (TP - 1);
  int h = __builtin_amdgcn_readfirstlane(tid >> 7);  // wave-uniform half
  int cbase = h * 13;  // h0 -> c 0..13 (writes 0..13), h1 -> c 13..26 (writes 1..13)
  const float* Fh = F + cbase;

  float acc[14];
#pragma unroll
  for (int c = 0; c < 14; ++c) acc[c] = 0.f;

#pragma unroll 4
  for (int k = 0; k < 144; ++k) {
    float fv = featT[k * TPP + p];
#pragma unroll
    for (int c = 0; c < 14; ++c) acc[c] = fmaf(fv, Fh[k * CC + c], acc[c]);
  }

  int sp = base + p;
  if (sp < n) {
    int oi = sidx[sp];
    float* o = out + (size_t)oi * CC + cbase;
    if (h == 0) o[0] = acc[0];
#pragma unroll
    for (int c = 1; c < 14; ++c) o[c] = acc[c];
  }
}

// ---------------- fallback (no workspace) ----------------
__global__ void __launch_bounds__(256) tensorf_naive(
    const float* __restrict__ xyz,
    const float* __restrict__ Pxy, const float* __restrict__ Pxz, const float* __restrict__ Pyz,
    const float* __restrict__ Vx, const float* __restrict__ Vy, const float* __restrict__ Vz,
    const float* __restrict__ F, float* __restrict__ out, int n) {
  int idx = blockIdx.x * blockDim.x + threadIdx.x;
  if (idx >= n) return;
  float x = xyz[idx * 3], y = xyz[idx * 3 + 1], z = xyz[idx * 3 + 2];
  Axis ax = axis_interp(x), ay = axis_interp(y), az = axis_interp(z);
  float acc[CC];
#pragma unroll
  for (int c = 0; c < CC; ++c) acc[c] = 0.f;
  const float* Ps[3] = {Pxy, Pxz, Pyz};
  const float* Vs[3] = {Vz, Vy, Vx};
  Axis A[3][2] = {{ax, ay}, {ax, az}, {ay, az}};
  Axis K[3] = {az, ay, ax};
#pragma unroll 1
  for (int s = 0; s < 3; ++s) {
    Axis ai = A[s][0], aj = A[s][1], ak = K[s];
    float fi = ai.f, fj = aj.f, fk = ak.f;
    float w00 = (1.f - fi) * (1.f - fj), w01 = (1.f - fi) * fj;
    float w10 = fi * (1.f - fj), w11 = fi * fj, omk = 1.f - fk;
#pragma unroll 1
    for (int r = 0; r < RR; ++r) {
      const float* pr = Ps[s] + r * HW2;
      float ft = (w00 * pr[ai.i0 * GG + aj.i0] + w01 * pr[ai.i0 * GG + aj.i1] +
                  w10 * pr[ai.i1 * GG + aj.i0] + w11 * pr[ai.i1 * GG + aj.i1]) *
                 (omk * Vs[s][r * GG + ak.i0] + fk * Vs[s][r * GG + ak.i1]);
      const float* Fr = F + (s * RR + r) * CC;
#pragma unroll
      for (int c = 0; c < CC; ++c) acc[c] = fmaf(ft, Fr[c], acc[c]);
    }
  }
  float* o = out + (size_t)idx * CC;
#pragma unroll
  for (int c = 0; c < CC; ++c) o[c] = acc[c];
}

extern "C" void kernel_launch(void* const* d_in, const int* in_sizes, int n_in,
                              void* d_out, int out_size, void* d_ws, size_t ws_size,
                              hipStream_t stream) {
  const float* xyz = (const float*)d_in[0];
  const float* pxy = (const float*)d_in[1];
  const float* pxz = (const float*)d_in[2];
  const float* pyz = (const float*)d_in[3];
  const float* vx = (const float*)d_in[4];
  const float* vy = (const float*)d_in[5];
  const float* vz = (const float*)d_in[6];
  const float* F = (const float*)d_in[7];
  float* out = (float*)d_out;
  int n = in_sizes[0] / 3;
  int nblk = (n + 255) / 256;

  size_t need = (size_t)(3 * NPLANE + 3 * NVEC) * sizeof(float) +
                (size_t)NBUCK * sizeof(int) + (size_t)n * sizeof(int);

  if (ws_size >= need) {
    float* w = (float*)d_ws;
    float* Txy = w;
    float* Txz = Txy + NPLANE;
    float* Tyz = Txz + NPLANE;
    float* Tx = Tyz + NPLANE;
    float* Ty = Tx + NVEC;
    float* Tz = Ty + NVEC;
    int* offs = (int*)(Tz + NVEC);
    int* sidx = offs + NBUCK;

    int tb = (HW2 + 255) / 256;
    dim3 tg(tb, 3);
    transpose_planes<<<tg, 256, 0, stream>>>(pxy, pxz, pyz, Txy, Txz, Tyz);
    int vb = (3 * NVEC + 255) / 256;
    transpose_vecs<<<vb, 256, 0, stream>>>(vx, vy, vz, Tx, Ty, Tz);

    hipMemsetAsync(offs, 0, (size_t)NBUCK * sizeof(int), stream);
    hist_kernel<<<nblk, 256, 0, stream>>>(xyz, n, offs);
    scan_kernel<<<1, 1024, 0, stream>>>(offs);
    scatter_kernel<<<nblk, 256, 0, stream>>>(xyz, n, offs, sidx);

    int ntile = (n + TP - 1) / TP;
    int chunkLen = (ntile + 7) / 8;
    tensorf_fused<<<chunkLen * 8, 256, 0, stream>>>(sidx, xyz, Txy, Txz, Tyz, Tx, Ty, Tz, F,
                                                    out, n, chunkLen);
  } else {
    tensorf_naive<<<nblk, 256, 0, stream>>>(xyz, pxy, pxz, pyz, vx, vy, vz, F, out, n);
  }
}